// Round 5
// baseline (128.289 us; speedup 1.0000x reference)
//
#include <hip/hip_runtime.h>

// B=32, C=8, L=2048, K=512, S=64, W=1985
// out[b,0,q] = max(0, max_w sum_c dot(xw_n[b,c,w,:], sn_n[c,q,:]) / 8)
//
// v6: counted-vmcnt software pipeline (T3/T4). v5's __syncthreads() drained
// vmcnt(0) twice per c-iter (m233's 2-phase pathology; MfmaUtil 30% = the
// guide's 28%). v6 uses raw s_barrier + hand-counted s_waitcnt vmcnt(10):
// per half-iter each wave issues exactly [loadA:10, STAGE:4] VMEM ops, so
// vmcnt(10) at the boundary retires the previous STAGE while the next
// A-loads stay in flight. Drain to 0 only in prologue + peeled tail.
// + s_setprio around the MFMA cluster (T5), + __launch_bounds__(256,3)
// (140 unified regs < 168 cap -> 3 blocks/CU, LDS 3x33KB fits).

#define B_ 32
#define C_ 8
#define L_ 2048
#define K_ 512
#define S_ 64
#define W_ 1985
#define XS_ 2176                      // padded f16 row stride (L_ + 128)

typedef _Float16 f16x8  __attribute__((ext_vector_type(8)));
typedef _Float16 f16x8u __attribute__((ext_vector_type(8), aligned(4)));
typedef float    f32x16 __attribute__((ext_vector_type(16)));

// ---- prologue (unchanged, harness-verified) ----
__global__ __launch_bounds__(256)
void prep_k(const float* __restrict__ x, const float* __restrict__ sh,
            _Float16* __restrict__ Bp, float* __restrict__ invn,
            _Float16* __restrict__ xh0, _Float16* __restrict__ xh1,
            float* __restrict__ out) {
    __shared__ float xr[L_];
    const int tid = threadIdx.x;
    const int blk = blockIdx.x;

    if (blk < 128) {
        const int sb   = blk * 4 + (tid >> 6);   // 0..511 = c(8) x kq(4) x nt(16)
        const int c    = sb >> 6;
        const int kq   = (sb >> 4) & 3;
        const int nt   = sb & 15;
        const int lane = tid & 63;
        const int half = lane >> 5;
        const int q    = nt * 32 + (lane & 31);

        const float4* sp = (const float4*)(sh + (size_t)(c * K_ + q) * S_);
        float ss = 0.f;
        #pragma unroll
        for (int i = 0; i < 8; ++i) {
            float4 v = sp[half * 8 + i];
            ss += v.x * v.x + v.y * v.y + v.z * v.z + v.w * v.w;
        }
        ss += __shfl_xor(ss, 32);
        float inv = 1.f / fmaxf(sqrtf(ss), 1e-8f);

        float4 u0 = sp[kq * 4 + half * 2];
        float4 u1 = sp[kq * 4 + half * 2 + 1];
        f16x8 o;
        o[0] = (_Float16)(u0.x * inv); o[1] = (_Float16)(u0.y * inv);
        o[2] = (_Float16)(u0.z * inv); o[3] = (_Float16)(u0.w * inv);
        o[4] = (_Float16)(u1.x * inv); o[5] = (_Float16)(u1.y * inv);
        o[6] = (_Float16)(u1.z * inv); o[7] = (_Float16)(u1.w * inv);
        ((f16x8*)Bp)[((c * 4 + kq) * 16 + nt) * 64 + lane] = o;
    } else {
        const int r = blk - 128;                 // 0..255 = b*8+c
        const float* xp = x + (size_t)r * L_;
        for (int i = tid; i < L_ / 4; i += 256)
            ((float4*)xr)[i] = ((const float4*)xp)[i];
        __syncthreads();

        float* ivp = invn + (size_t)r * L_;
        const int w0 = tid * 8;
        float ss = 0.f;
        if (w0 < W_) {
            #pragma unroll
            for (int j = 0; j < S_; ++j) { float v = xr[w0 + j]; ss += v * v; }
        }
        #pragma unroll
        for (int u = 0; u < 8; ++u) {
            int w = w0 + u;
            float o = 0.f;
            if (u > 0 && w < W_)
                ss += xr[w + 63] * xr[w + 63] - xr[w - 1] * xr[w - 1];
            if (w < W_) o = 0.125f / fmaxf(sqrtf(ss), 1e-8f);
            if (w < L_) ivp[w] = o;
        }

        _Float16* p0 = xh0 + (size_t)r * XS_;
        _Float16* p1 = xh1 + (size_t)r * XS_;
        for (int i = tid; i < XS_ / 8; i += 256) {
            f16x8 o0, o1;
            #pragma unroll
            for (int j = 0; j < 8; ++j) {
                int e = i * 8 + j;
                o0[j] = (_Float16)((e     < L_) ? xr[e]     : 0.f);
                o1[j] = (_Float16)((e + 1 < L_) ? xr[e + 1] : 0.f);
            }
            ((f16x8*)p0)[i] = o0;
            ((f16x8*)p1)[i] = o1;
        }
        if (r < 64) out[r * 256 + tid] = 0.f;    // zero output
    }
}

// global -> LDS direct copy, 16B per lane (dest = uniform base + lane*16)
__device__ __forceinline__ void glds16(const void* g, void* l) {
    __builtin_amdgcn_global_load_lds(
        (const __attribute__((address_space(1))) unsigned int*)g,
        (__attribute__((address_space(3))) unsigned int*)l, 16, 0, 0);
}

// A fragments + inv-norms for channel c into NAMED register buffers (10 VMEM)
__device__ __forceinline__ void loadA(
    int c, const _Float16* __restrict__ xbase, const float* __restrict__ ivbase,
    int m0, int m1, f16x8 (&ar)[8], float (&iv)[2])
{
    iv[0] = ivbase[(size_t)c * L_ + m0];         // 0 for invalid windows
    iv[1] = ivbase[(size_t)c * L_ + m1];
    const _Float16* xp = xbase + (size_t)c * XS_;
    #pragma unroll
    for (int mt = 0; mt < 2; ++mt)
        #pragma unroll
        for (int ks = 0; ks < 4; ++ks)
            ar[mt * 4 + ks] = *(const f16x8u*)(xp + mt * 32 + ks * 16);
}

// 8 ds_read_b128 (B panel from LDS) + scale A + 16 MFMAs (setprio-wrapped)
__device__ __forceinline__ void compC(
    const f16x8* __restrict__ bsl, int lane, int nw,
    const f16x8 (&ar)[8], const float (&iv)[2], f32x16 (&acc)[2][2])
{
    f16x8 bf[8];
    #pragma unroll
    for (int ks = 0; ks < 4; ++ks)
        #pragma unroll
        for (int nt = 0; nt < 2; ++nt)
            bf[ks * 2 + nt] = bsl[(ks * 4 + nw * 2 + nt) * 64 + lane];

    const _Float16 h0 = (_Float16)iv[0], h1 = (_Float16)iv[1];
    f16x8 is0, is1;
    #pragma unroll
    for (int j = 0; j < 8; ++j) { is0[j] = h0; is1[j] = h1; }

    __builtin_amdgcn_s_setprio(1);
    #pragma unroll
    for (int ks = 0; ks < 4; ++ks) {
        f16x8 a0 = ar[0 * 4 + ks] * is0;          // v_pk_mul_f16 x4
        f16x8 a1 = ar[1 * 4 + ks] * is1;
        #pragma unroll
        for (int nt = 0; nt < 2; ++nt) {
            acc[0][nt] = __builtin_amdgcn_mfma_f32_32x32x16_f16(
                a0, bf[ks * 2 + nt], acc[0][nt], 0, 0, 0);
            acc[1][nt] = __builtin_amdgcn_mfma_f32_32x32x16_f16(
                a1, bf[ks * 2 + nt], acc[1][nt], 0, 0, 0);
        }
    }
    __builtin_amdgcn_s_setprio(0);
}

// ---- main: LDS-staged B, counted-vmcnt pipeline, raw barriers ----
// grid (16 wt, 4 ng, 32 b) = 2048 blocks, 4 waves (mg x nw = 2x2).
// Wave: 64 windows (2x32) x 64 q (2x32); acc = 4 x f32x16 = 64 AGPR.
// Half-iteration: compC(cur) -> loadA(c+2) -> vmcnt(10) -> s_barrier ->
// STAGE(c+2, cur). vmcnt(10) retires the previous half's STAGE (the only
// ops newer are this half's 10 A-loads); the asm memory clobbers pin the
// [loadA .. asm .. STAGE] issue order. Drain vmcnt(0) only at prologue/tail.
__global__ __launch_bounds__(256, 3)
void mcs_k(const _Float16* __restrict__ xh0, const _Float16* __restrict__ xh1,
           const _Float16* __restrict__ Bp, const float* __restrict__ invn,
           float* __restrict__ out) {
    const int wt  = blockIdx.x;
    const int ng  = blockIdx.y;           // 0..3, 128-q panel
    const int b   = blockIdx.z;
    const int tid = threadIdx.x;
    const int lane = tid & 63;
    const int wv   = tid >> 6;
    const int mg   = wv >> 1;             // window subgroup
    const int nw   = wv & 1;              // q half of panel

    const int l31 = lane & 31;
    const int lh  = lane >> 5;
    const int Wb  = wt * 128 + mg * 64;   // wave's window base
    const int m0  = Wb + l31;
    const int m1  = Wb + 32 + l31;

    __shared__ f16x8 Bs[2][16][64];       // 2 x 16KB B-panel buffers
    __shared__ float red[2][2][32];       // cross-wave max

    // parity-selected x base keeps every f16x8 load 4B-aligned
    const _Float16* xb = (l31 & 1) ? (xh1 - 1) : xh0;
    const _Float16* xbase = xb + (size_t)b * C_ * XS_ + Wb + l31 + lh * 8;
    const float*   ivbase = invn + (size_t)b * C_ * L_;
    // staging source: wave wv covers ks=wv, units nt=0..3 of this ng panel
    const f16x8*   sg = (const f16x8*)Bp + ((wv * 16 + ng * 4) * 64) + lane;

    f32x16 acc[2][2];
    #pragma unroll
    for (int mt = 0; mt < 2; ++mt)
        #pragma unroll
        for (int nt = 0; nt < 2; ++nt)
            #pragma unroll
            for (int r = 0; r < 16; ++r) acc[mt][nt][r] = 0.f;

    f16x8 aA[8], aB[8];
    float ivA[2], ivB[2];

    // stage B-panel for channel c into buffer buf (4 VMEM / wave)
    #define STAGE(c, buf)                                              \
        { _Pragma("unroll")                                            \
          for (int u = 0; u < 4; ++u)                                  \
              glds16(sg + ((c) * 64 + u) * 64, &Bs[buf][wv * 4 + u][0]); }

    // prologue: stage c=0,1 and load A0,A1; single full drain; barrier
    STAGE(0, 0);
    STAGE(1, 1);
    loadA(0, xbase, ivbase, m0, m1, aA, ivA);
    loadA(1, xbase, ivbase, m0, m1, aB, ivB);
    asm volatile("s_waitcnt vmcnt(0)" ::: "memory");
    __builtin_amdgcn_s_barrier();

    #pragma unroll 1
    for (int cp = 0; cp < 3; ++cp) {
        const int c0 = cp * 2;
        // even half: c = c0, buf0, aA
        compC(&Bs[0][0][0], lane, nw, aA, ivA, acc);
        loadA(c0 + 2, xbase, ivbase, m0, m1, aA, ivA);   // after last aA use
        asm volatile("s_waitcnt vmcnt(10)" ::: "memory"); // STAGE(c0+1) landed
        __builtin_amdgcn_s_barrier();
        STAGE(c0 + 2, 0);                                 // buf0 free now
        // odd half: c = c0+1, buf1, aB
        compC(&Bs[1][0][0], lane, nw, aB, ivB, acc);
        loadA(c0 + 3, xbase, ivbase, m0, m1, aB, ivB);
        asm volatile("s_waitcnt vmcnt(10)" ::: "memory"); // STAGE(c0+2) landed
        __builtin_amdgcn_s_barrier();
        STAGE(c0 + 3, 1);
    }
    // peeled tail: c = 6 (buf0/aA), then c = 7 (buf1/aB)
    compC(&Bs[0][0][0], lane, nw, aA, ivA, acc);
    asm volatile("s_waitcnt vmcnt(0)" ::: "memory");      // STAGE(7) landed
    __builtin_amdgcn_s_barrier();
    compC(&Bs[1][0][0], lane, nw, aB, ivB, acc);
    #undef STAGE

    // epilogue: relu + max over windows. C/D: col(q) = lane&31, rows = windows;
    // reduce rows per lane, fold lane^32, cross-wave (mg) max via LDS.
    float m[2];
    #pragma unroll
    for (int nt = 0; nt < 2; ++nt) {
        float v = 0.f;
        #pragma unroll
        for (int mt = 0; mt < 2; ++mt)
            #pragma unroll
            for (int r = 0; r < 16; ++r) v = fmaxf(v, acc[mt][nt][r]);
        v = fmaxf(v, __shfl_xor(v, 32));
        m[nt] = v;
    }

    if (mg == 0 && lane < 32) {
        red[nw][0][l31] = m[0];
        red[nw][1][l31] = m[1];
    }
    __syncthreads();
    if (mg == 1 && lane < 32) {
        #pragma unroll
        for (int nt = 0; nt < 2; ++nt) {
            float v = fmaxf(m[nt], red[nw][nt][l31]);
            atomicMax((unsigned int*)(out + (size_t)b * K_ + ng * 128 + nw * 64 + nt * 32 + l31),
                      __float_as_uint(v));   // values >= 0, uint-max valid
        }
    }
}

extern "C" void kernel_launch(void* const* d_in, const int* in_sizes, int n_in,
                              void* d_out, int out_size, void* d_ws, size_t ws_size,
                              hipStream_t stream) {
    const float* x  = (const float*)d_in[0];   // (32, 8, 2048) fp32
    const float* sh = (const float*)d_in[1];   // (8, 512, 64) fp32
    float* out = (float*)d_out;                // (32, 1, 512) fp32

    // workspace: Bp 512KB | invn 2MB | xh0 ~1.06MB | xh1 ~1.06MB
    _Float16* Bp   = (_Float16*)d_ws;
    float*    invn = (float*)((char*)d_ws + (512 << 10));
    _Float16* xh0  = (_Float16*)((char*)d_ws + (512 << 10) + (2 << 20));
    _Float16* xh1  = xh0 + (size_t)B_ * C_ * XS_;

    prep_k<<<dim3(384), dim3(256), 0, stream>>>(x, sh, Bp, invn, xh0, xh1, out);
    mcs_k<<<dim3(16, 4, B_), dim3(256), 0, stream>>>(xh0, xh1, Bp, invn, out);
}

// Round 6
// 102.754 us; speedup vs baseline: 1.2485x; 1.2485x over previous
//
#include <hip/hip_runtime.h>

// B=32, C=8, L=2048, K=512, S=64, W=1985
// out[b,0,q] = max(0, max_w sum_c dot(xw_n[b,c,w,:], sn_n[c,q,:]) / 8)
//
// v7: v6's counted-vmcnt pipeline (T3/T4) + setprio (T5), with the v6
// regression cause removed: __launch_bounds__(256,3) forced ~180 unified
// regs into a 168-reg budget -> scratch spills (WRITE_SIZE 1MB -> 112MB).
// Back to (256,2): 256-reg cap, no spill. Everything else identical to v6
// -- clean A/B of the counted-vmcnt schedule vs v5's drain-to-zero (44.6us).

#define B_ 32
#define C_ 8
#define L_ 2048
#define K_ 512
#define S_ 64
#define W_ 1985
#define XS_ 2176                      // padded f16 row stride (L_ + 128)

typedef _Float16 f16x8  __attribute__((ext_vector_type(8)));
typedef _Float16 f16x8u __attribute__((ext_vector_type(8), aligned(4)));
typedef float    f32x16 __attribute__((ext_vector_type(16)));

// ---- prologue (unchanged, harness-verified) ----
__global__ __launch_bounds__(256)
void prep_k(const float* __restrict__ x, const float* __restrict__ sh,
            _Float16* __restrict__ Bp, float* __restrict__ invn,
            _Float16* __restrict__ xh0, _Float16* __restrict__ xh1,
            float* __restrict__ out) {
    __shared__ float xr[L_];
    const int tid = threadIdx.x;
    const int blk = blockIdx.x;

    if (blk < 128) {
        const int sb   = blk * 4 + (tid >> 6);   // 0..511 = c(8) x kq(4) x nt(16)
        const int c    = sb >> 6;
        const int kq   = (sb >> 4) & 3;
        const int nt   = sb & 15;
        const int lane = tid & 63;
        const int half = lane >> 5;
        const int q    = nt * 32 + (lane & 31);

        const float4* sp = (const float4*)(sh + (size_t)(c * K_ + q) * S_);
        float ss = 0.f;
        #pragma unroll
        for (int i = 0; i < 8; ++i) {
            float4 v = sp[half * 8 + i];
            ss += v.x * v.x + v.y * v.y + v.z * v.z + v.w * v.w;
        }
        ss += __shfl_xor(ss, 32);
        float inv = 1.f / fmaxf(sqrtf(ss), 1e-8f);

        float4 u0 = sp[kq * 4 + half * 2];
        float4 u1 = sp[kq * 4 + half * 2 + 1];
        f16x8 o;
        o[0] = (_Float16)(u0.x * inv); o[1] = (_Float16)(u0.y * inv);
        o[2] = (_Float16)(u0.z * inv); o[3] = (_Float16)(u0.w * inv);
        o[4] = (_Float16)(u1.x * inv); o[5] = (_Float16)(u1.y * inv);
        o[6] = (_Float16)(u1.z * inv); o[7] = (_Float16)(u1.w * inv);
        ((f16x8*)Bp)[((c * 4 + kq) * 16 + nt) * 64 + lane] = o;
    } else {
        const int r = blk - 128;                 // 0..255 = b*8+c
        const float* xp = x + (size_t)r * L_;
        for (int i = tid; i < L_ / 4; i += 256)
            ((float4*)xr)[i] = ((const float4*)xp)[i];
        __syncthreads();

        float* ivp = invn + (size_t)r * L_;
        const int w0 = tid * 8;
        float ss = 0.f;
        if (w0 < W_) {
            #pragma unroll
            for (int j = 0; j < S_; ++j) { float v = xr[w0 + j]; ss += v * v; }
        }
        #pragma unroll
        for (int u = 0; u < 8; ++u) {
            int w = w0 + u;
            float o = 0.f;
            if (u > 0 && w < W_)
                ss += xr[w + 63] * xr[w + 63] - xr[w - 1] * xr[w - 1];
            if (w < W_) o = 0.125f / fmaxf(sqrtf(ss), 1e-8f);
            if (w < L_) ivp[w] = o;
        }

        _Float16* p0 = xh0 + (size_t)r * XS_;
        _Float16* p1 = xh1 + (size_t)r * XS_;
        for (int i = tid; i < XS_ / 8; i += 256) {
            f16x8 o0, o1;
            #pragma unroll
            for (int j = 0; j < 8; ++j) {
                int e = i * 8 + j;
                o0[j] = (_Float16)((e     < L_) ? xr[e]     : 0.f);
                o1[j] = (_Float16)((e + 1 < L_) ? xr[e + 1] : 0.f);
            }
            ((f16x8*)p0)[i] = o0;
            ((f16x8*)p1)[i] = o1;
        }
        if (r < 64) out[r * 256 + tid] = 0.f;    // zero output
    }
}

// global -> LDS direct copy, 16B per lane (dest = uniform base + lane*16)
__device__ __forceinline__ void glds16(const void* g, void* l) {
    __builtin_amdgcn_global_load_lds(
        (const __attribute__((address_space(1))) unsigned int*)g,
        (__attribute__((address_space(3))) unsigned int*)l, 16, 0, 0);
}

// A fragments + inv-norms for channel c into NAMED register buffers (10 VMEM)
__device__ __forceinline__ void loadA(
    int c, const _Float16* __restrict__ xbase, const float* __restrict__ ivbase,
    int m0, int m1, f16x8 (&ar)[8], float (&iv)[2])
{
    iv[0] = ivbase[(size_t)c * L_ + m0];         // 0 for invalid windows
    iv[1] = ivbase[(size_t)c * L_ + m1];
    const _Float16* xp = xbase + (size_t)c * XS_;
    #pragma unroll
    for (int mt = 0; mt < 2; ++mt)
        #pragma unroll
        for (int ks = 0; ks < 4; ++ks)
            ar[mt * 4 + ks] = *(const f16x8u*)(xp + mt * 32 + ks * 16);
}

// 8 ds_read_b128 (B panel from LDS) + scale A + 16 MFMAs (setprio-wrapped)
__device__ __forceinline__ void compC(
    const f16x8* __restrict__ bsl, int lane, int nw,
    const f16x8 (&ar)[8], const float (&iv)[2], f32x16 (&acc)[2][2])
{
    f16x8 bf[8];
    #pragma unroll
    for (int ks = 0; ks < 4; ++ks)
        #pragma unroll
        for (int nt = 0; nt < 2; ++nt)
            bf[ks * 2 + nt] = bsl[(ks * 4 + nw * 2 + nt) * 64 + lane];

    const _Float16 h0 = (_Float16)iv[0], h1 = (_Float16)iv[1];
    f16x8 is0, is1;
    #pragma unroll
    for (int j = 0; j < 8; ++j) { is0[j] = h0; is1[j] = h1; }

    __builtin_amdgcn_s_setprio(1);
    #pragma unroll
    for (int ks = 0; ks < 4; ++ks) {
        f16x8 a0 = ar[0 * 4 + ks] * is0;          // v_pk_mul_f16 x4
        f16x8 a1 = ar[1 * 4 + ks] * is1;
        #pragma unroll
        for (int nt = 0; nt < 2; ++nt) {
            acc[0][nt] = __builtin_amdgcn_mfma_f32_32x32x16_f16(
                a0, bf[ks * 2 + nt], acc[0][nt], 0, 0, 0);
            acc[1][nt] = __builtin_amdgcn_mfma_f32_32x32x16_f16(
                a1, bf[ks * 2 + nt], acc[1][nt], 0, 0, 0);
        }
    }
    __builtin_amdgcn_s_setprio(0);
}

// ---- main: LDS-staged B, counted-vmcnt pipeline, raw barriers ----
// grid (16 wt, 4 ng, 32 b) = 2048 blocks, 4 waves (mg x nw = 2x2).
// Wave: 64 windows (2x32) x 64 q (2x32); acc = 4 x f32x16 = 64 AGPR.
// Half-iteration: compC(cur) -> loadA(c+2) -> vmcnt(10) -> s_barrier ->
// STAGE(c+2, cur). vmcnt(10) retires the previous half's STAGE (the only
// ops newer are this half's 10 A-loads); the asm memory clobbers pin the
// [loadA .. asm .. STAGE] issue order. Drain vmcnt(0) only at prologue/tail.
__global__ __launch_bounds__(256, 2)
void mcs_k(const _Float16* __restrict__ xh0, const _Float16* __restrict__ xh1,
           const _Float16* __restrict__ Bp, const float* __restrict__ invn,
           float* __restrict__ out) {
    const int wt  = blockIdx.x;
    const int ng  = blockIdx.y;           // 0..3, 128-q panel
    const int b   = blockIdx.z;
    const int tid = threadIdx.x;
    const int lane = tid & 63;
    const int wv   = tid >> 6;
    const int mg   = wv >> 1;             // window subgroup
    const int nw   = wv & 1;              // q half of panel

    const int l31 = lane & 31;
    const int lh  = lane >> 5;
    const int Wb  = wt * 128 + mg * 64;   // wave's window base
    const int m0  = Wb + l31;
    const int m1  = Wb + 32 + l31;

    __shared__ f16x8 Bs[2][16][64];       // 2 x 16KB B-panel buffers
    __shared__ float red[2][2][32];       // cross-wave max

    // parity-selected x base keeps every f16x8 load 4B-aligned
    const _Float16* xb = (l31 & 1) ? (xh1 - 1) : xh0;
    const _Float16* xbase = xb + (size_t)b * C_ * XS_ + Wb + l31 + lh * 8;
    const float*   ivbase = invn + (size_t)b * C_ * L_;
    // staging source: wave wv covers ks=wv, units nt=0..3 of this ng panel
    const f16x8*   sg = (const f16x8*)Bp + ((wv * 16 + ng * 4) * 64) + lane;

    f32x16 acc[2][2];
    #pragma unroll
    for (int mt = 0; mt < 2; ++mt)
        #pragma unroll
        for (int nt = 0; nt < 2; ++nt)
            #pragma unroll
            for (int r = 0; r < 16; ++r) acc[mt][nt][r] = 0.f;

    f16x8 aA[8], aB[8];
    float ivA[2], ivB[2];

    // stage B-panel for channel c into buffer buf (4 VMEM / wave)
    #define STAGE(c, buf)                                              \
        { _Pragma("unroll")                                            \
          for (int u = 0; u < 4; ++u)                                  \
              glds16(sg + ((c) * 64 + u) * 64, &Bs[buf][wv * 4 + u][0]); }

    // prologue: stage c=0,1 and load A0,A1; single full drain; barrier
    STAGE(0, 0);
    STAGE(1, 1);
    loadA(0, xbase, ivbase, m0, m1, aA, ivA);
    loadA(1, xbase, ivbase, m0, m1, aB, ivB);
    asm volatile("s_waitcnt vmcnt(0)" ::: "memory");
    __builtin_amdgcn_s_barrier();

    #pragma unroll 1
    for (int cp = 0; cp < 3; ++cp) {
        const int c0 = cp * 2;
        // even half: c = c0, buf0, aA
        compC(&Bs[0][0][0], lane, nw, aA, ivA, acc);
        loadA(c0 + 2, xbase, ivbase, m0, m1, aA, ivA);   // after last aA use
        asm volatile("s_waitcnt vmcnt(10)" ::: "memory"); // STAGE(c0+1) landed
        __builtin_amdgcn_s_barrier();
        STAGE(c0 + 2, 0);                                 // buf0 free now
        // odd half: c = c0+1, buf1, aB
        compC(&Bs[1][0][0], lane, nw, aB, ivB, acc);
        loadA(c0 + 3, xbase, ivbase, m0, m1, aB, ivB);
        asm volatile("s_waitcnt vmcnt(10)" ::: "memory"); // STAGE(c0+2) landed
        __builtin_amdgcn_s_barrier();
        STAGE(c0 + 3, 1);
    }
    // peeled tail: c = 6 (buf0/aA), then c = 7 (buf1/aB)
    compC(&Bs[0][0][0], lane, nw, aA, ivA, acc);
    asm volatile("s_waitcnt vmcnt(0)" ::: "memory");      // STAGE(7) landed
    __builtin_amdgcn_s_barrier();
    compC(&Bs[1][0][0], lane, nw, aB, ivB, acc);
    #undef STAGE

    // epilogue: relu + max over windows. C/D: col(q) = lane&31, rows = windows;
    // reduce rows per lane, fold lane^32, cross-wave (mg) max via LDS.
    float m[2];
    #pragma unroll
    for (int nt = 0; nt < 2; ++nt) {
        float v = 0.f;
        #pragma unroll
        for (int mt = 0; mt < 2; ++mt)
            #pragma unroll
            for (int r = 0; r < 16; ++r) v = fmaxf(v, acc[mt][nt][r]);
        v = fmaxf(v, __shfl_xor(v, 32));
        m[nt] = v;
    }

    if (mg == 0 && lane < 32) {
        red[nw][0][l31] = m[0];
        red[nw][1][l31] = m[1];
    }
    __syncthreads();
    if (mg == 1 && lane < 32) {
        #pragma unroll
        for (int nt = 0; nt < 2; ++nt) {
            float v = fmaxf(m[nt], red[nw][nt][l31]);
            atomicMax((unsigned int*)(out + (size_t)b * K_ + ng * 128 + nw * 64 + nt * 32 + l31),
                      __float_as_uint(v));   // values >= 0, uint-max valid
        }
    }
}

extern "C" void kernel_launch(void* const* d_in, const int* in_sizes, int n_in,
                              void* d_out, int out_size, void* d_ws, size_t ws_size,
                              hipStream_t stream) {
    const float* x  = (const float*)d_in[0];   // (32, 8, 2048) fp32
    const float* sh = (const float*)d_in[1];   // (8, 512, 64) fp32
    float* out = (float*)d_out;                // (32, 1, 512) fp32

    // workspace: Bp 512KB | invn 2MB | xh0 ~1.06MB | xh1 ~1.06MB
    _Float16* Bp   = (_Float16*)d_ws;
    float*    invn = (float*)((char*)d_ws + (512 << 10));
    _Float16* xh0  = (_Float16*)((char*)d_ws + (512 << 10) + (2 << 20));
    _Float16* xh1  = xh0 + (size_t)B_ * C_ * XS_;

    prep_k<<<dim3(384), dim3(256), 0, stream>>>(x, sh, Bp, invn, xh0, xh1, out);
    mcs_k<<<dim3(16, 4, B_), dim3(256), 0, stream>>>(xh0, xh1, Bp, invn, out);
}

// Round 7
// 98.807 us; speedup vs baseline: 1.2984x; 1.0399x over previous
//
#include <hip/hip_runtime.h>

// B=32, C=8, L=2048, K=512, S=64, W=1985
// out[b,0,q] = max(0, max_w sum_c dot(xw_n[b,c,w,:], sn_n[c,q,:]) / 8)
//
// v8: barrier-free main loop with PERSISTENT LDS B-panel. v5/v6/v7 all hit
// the 2-phase ceiling (27-30% MfmaUtil; guide m233: stage->barrier->compute
// skeleton is ~72% overhead regardless of vmcnt counting). Fix: each block
// takes a 64-q slice so its whole 8-channel B-panel is 64 KB -> staged ONCE
// (global_load_lds), one __syncthreads, then c-loop runs with NO barriers:
// B from LDS (8 ds_read_b128/c, conflict-free), A register-prefetched one c
// ahead (named buffers). Waves drift freely; MFMA is the dominant pipe
// (per SIMD per c-round: 1024cy MFMA vs 192cy DS, ~80cy TA).

#define B_ 32
#define C_ 8
#define L_ 2048
#define K_ 512
#define S_ 64
#define W_ 1985
#define XS_ 2176                      // padded f16 row stride (L_ + 128)

typedef _Float16 f16x8  __attribute__((ext_vector_type(8)));
typedef _Float16 f16x8u __attribute__((ext_vector_type(8), aligned(4)));
typedef float    f32x16 __attribute__((ext_vector_type(16)));

// ---- prologue (unchanged, harness-verified) ----
__global__ __launch_bounds__(256)
void prep_k(const float* __restrict__ x, const float* __restrict__ sh,
            _Float16* __restrict__ Bp, float* __restrict__ invn,
            _Float16* __restrict__ xh0, _Float16* __restrict__ xh1,
            float* __restrict__ out) {
    __shared__ float xr[L_];
    const int tid = threadIdx.x;
    const int blk = blockIdx.x;

    if (blk < 128) {
        const int sb   = blk * 4 + (tid >> 6);   // 0..511 = c(8) x kq(4) x nt(16)
        const int c    = sb >> 6;
        const int kq   = (sb >> 4) & 3;
        const int nt   = sb & 15;
        const int lane = tid & 63;
        const int half = lane >> 5;
        const int q    = nt * 32 + (lane & 31);

        const float4* sp = (const float4*)(sh + (size_t)(c * K_ + q) * S_);
        float ss = 0.f;
        #pragma unroll
        for (int i = 0; i < 8; ++i) {
            float4 v = sp[half * 8 + i];
            ss += v.x * v.x + v.y * v.y + v.z * v.z + v.w * v.w;
        }
        ss += __shfl_xor(ss, 32);
        float inv = 1.f / fmaxf(sqrtf(ss), 1e-8f);

        float4 u0 = sp[kq * 4 + half * 2];
        float4 u1 = sp[kq * 4 + half * 2 + 1];
        f16x8 o;
        o[0] = (_Float16)(u0.x * inv); o[1] = (_Float16)(u0.y * inv);
        o[2] = (_Float16)(u0.z * inv); o[3] = (_Float16)(u0.w * inv);
        o[4] = (_Float16)(u1.x * inv); o[5] = (_Float16)(u1.y * inv);
        o[6] = (_Float16)(u1.z * inv); o[7] = (_Float16)(u1.w * inv);
        ((f16x8*)Bp)[((c * 4 + kq) * 16 + nt) * 64 + lane] = o;
    } else {
        const int r = blk - 128;                 // 0..255 = b*8+c
        const float* xp = x + (size_t)r * L_;
        for (int i = tid; i < L_ / 4; i += 256)
            ((float4*)xr)[i] = ((const float4*)xp)[i];
        __syncthreads();

        float* ivp = invn + (size_t)r * L_;
        const int w0 = tid * 8;
        float ss = 0.f;
        if (w0 < W_) {
            #pragma unroll
            for (int j = 0; j < S_; ++j) { float v = xr[w0 + j]; ss += v * v; }
        }
        #pragma unroll
        for (int u = 0; u < 8; ++u) {
            int w = w0 + u;
            float o = 0.f;
            if (u > 0 && w < W_)
                ss += xr[w + 63] * xr[w + 63] - xr[w - 1] * xr[w - 1];
            if (w < W_) o = 0.125f / fmaxf(sqrtf(ss), 1e-8f);
            if (w < L_) ivp[w] = o;
        }

        _Float16* p0 = xh0 + (size_t)r * XS_;
        _Float16* p1 = xh1 + (size_t)r * XS_;
        for (int i = tid; i < XS_ / 8; i += 256) {
            f16x8 o0, o1;
            #pragma unroll
            for (int j = 0; j < 8; ++j) {
                int e = i * 8 + j;
                o0[j] = (_Float16)((e     < L_) ? xr[e]     : 0.f);
                o1[j] = (_Float16)((e + 1 < L_) ? xr[e + 1] : 0.f);
            }
            ((f16x8*)p0)[i] = o0;
            ((f16x8*)p1)[i] = o1;
        }
        if (r < 64) out[r * 256 + tid] = 0.f;    // zero output
    }
}

// global -> LDS direct copy, 16B per lane (dest = uniform base + lane*16)
__device__ __forceinline__ void glds16(const void* g, void* l) {
    __builtin_amdgcn_global_load_lds(
        (const __attribute__((address_space(1))) unsigned int*)g,
        (__attribute__((address_space(3))) unsigned int*)l, 16, 0, 0);
}

// A fragments + inv-norms for channel c into NAMED register buffers (10 VMEM)
__device__ __forceinline__ void loadA(
    int c, const _Float16* __restrict__ xbase, const float* __restrict__ ivbase,
    int m0, int m1, f16x8 (&ar)[8], float (&iv)[2])
{
    iv[0] = ivbase[(size_t)c * L_ + m0];         // 0 for invalid windows
    iv[1] = ivbase[(size_t)c * L_ + m1];
    const _Float16* xp = xbase + (size_t)c * XS_;
    #pragma unroll
    for (int mt = 0; mt < 2; ++mt)
        #pragma unroll
        for (int ks = 0; ks < 4; ++ks)
            ar[mt * 4 + ks] = *(const f16x8u*)(xp + mt * 32 + ks * 16);
}

// 8 ds_read_b128 (B panel, LDS-persistent) + scale A + 16 MFMAs
__device__ __forceinline__ void compC(
    int c, const f16x8* __restrict__ bsl, int lane,
    const f16x8 (&ar)[8], const float (&iv)[2], f32x16 (&acc)[2][2])
{
    // Bs unit e = c*8 + ks*2 + nt; lane-contiguous 16B reads, conflict-free
    f16x8 bf[8];
    #pragma unroll
    for (int ks = 0; ks < 4; ++ks)
        #pragma unroll
        for (int nt = 0; nt < 2; ++nt)
            bf[ks * 2 + nt] = bsl[(c * 8 + ks * 2 + nt) * 64 + lane];

    const _Float16 h0 = (_Float16)iv[0], h1 = (_Float16)iv[1];
    f16x8 is0, is1;
    #pragma unroll
    for (int j = 0; j < 8; ++j) { is0[j] = h0; is1[j] = h1; }

    __builtin_amdgcn_s_setprio(1);
    #pragma unroll
    for (int ks = 0; ks < 4; ++ks) {
        f16x8 a0 = ar[0 * 4 + ks] * is0;          // v_pk_mul_f16 x4
        f16x8 a1 = ar[1 * 4 + ks] * is1;
        #pragma unroll
        for (int nt = 0; nt < 2; ++nt) {
            acc[0][nt] = __builtin_amdgcn_mfma_f32_32x32x16_f16(
                a0, bf[ks * 2 + nt], acc[0][nt], 0, 0, 0);
            acc[1][nt] = __builtin_amdgcn_mfma_f32_32x32x16_f16(
                a1, bf[ks * 2 + nt], acc[1][nt], 0, 0, 0);
        }
    }
    __builtin_amdgcn_s_setprio(0);
}

// ---- main: persistent-LDS B, single barrier, free-running c-loop ----
// grid (8 wt, 8 ng, 32 b) = 2048 blocks, 4 waves = 4 window subgroups.
// Block: 256 windows x 64 q. Wave: 64 windows (2x32) x 64 q (2x32);
// acc = 4 x f32x16 = 64 AGPR. Stage the block's full B-panel (8c x 64q =
// 64 units x 1KB) once via global_load_lds (16/wave), one __syncthreads,
// then: for c { compC(c) from LDS; loadA(c+1) reg-prefetch } barrier-free.
__global__ __launch_bounds__(256, 2)
void mcs_k(const _Float16* __restrict__ xh0, const _Float16* __restrict__ xh1,
           const _Float16* __restrict__ Bp, const float* __restrict__ invn,
           float* __restrict__ out) {
    const int wt  = blockIdx.x;           // 0..7  256-window tile
    const int ng  = blockIdx.y;           // 0..7  64-q panel
    const int b   = blockIdx.z;
    const int tid = threadIdx.x;
    const int lane = tid & 63;
    const int wv   = tid >> 6;            // window subgroup 0..3

    const int l31 = lane & 31;
    const int lh  = lane >> 5;
    const int Wb  = wt * 256 + wv * 64;   // wave's window base (max 1984)
    const int m0  = Wb + l31;
    const int m1  = Wb + 32 + l31;

    __shared__ f16x8 Bs[64][64];          // 64 KB: unit e = c*8+ks*2+nt

    // ---- stage the block's B-panel once: wave wv covers e = wv*16..+15 ----
    {
        const f16x8* bp = (const f16x8*)Bp;
        #pragma unroll
        for (int u = 0; u < 16; ++u) {
            const int e   = wv * 16 + u;
            const int c   = e >> 3;
            const int sub = e & 7;                    // ks*2 + nt
            const int src = ((c * 4 + (sub >> 1)) * 16 + ng * 2 + (sub & 1)) * 64;
            glds16(bp + src + lane, &Bs[e][0]);
        }
    }

    // parity-selected x base keeps every f16x8 load 4B-aligned
    const _Float16* xb = (l31 & 1) ? (xh1 - 1) : xh0;
    const _Float16* xbase = xb + (size_t)b * C_ * XS_ + Wb + l31 + lh * 8;
    const float*   ivbase = invn + (size_t)b * C_ * L_;

    f32x16 acc[2][2];
    #pragma unroll
    for (int mt = 0; mt < 2; ++mt)
        #pragma unroll
        for (int nt = 0; nt < 2; ++nt)
            #pragma unroll
            for (int r = 0; r < 16; ++r) acc[mt][nt][r] = 0.f;

    f16x8 aA[8], aB[8];
    float ivA[2], ivB[2];

    loadA(0, xbase, ivbase, m0, m1, aA, ivA);   // overlaps the staging
    __syncthreads();                            // B-panel ready (vmcnt drained)

    #pragma unroll 1
    for (int cp = 0; cp < 4; ++cp) {
        const int c0 = cp * 2;
        loadA(c0 + 1, xbase, ivbase, m0, m1, aB, ivB);
        compC(c0, &Bs[0][0], lane, aA, ivA, acc);
        if (cp < 3)
            loadA(c0 + 2, xbase, ivbase, m0, m1, aA, ivA);
        compC(c0 + 1, &Bs[0][0], lane, aB, ivB, acc);
    }

    // epilogue: relu + max over windows (invalid windows exactly 0).
    // C/D: col(q) = lane&31, rows = windows; per-wave atomics (waves cover
    // disjoint windows of the same q -> atomicMax combines).
    #pragma unroll
    for (int nt = 0; nt < 2; ++nt) {
        float v = 0.f;
        #pragma unroll
        for (int mt = 0; mt < 2; ++mt)
            #pragma unroll
            for (int r = 0; r < 16; ++r) v = fmaxf(v, acc[mt][nt][r]);
        v = fmaxf(v, __shfl_xor(v, 32));
        if (lane < 32)
            atomicMax((unsigned int*)(out + (size_t)b * K_ + ng * 64 + nt * 32 + l31),
                      __float_as_uint(v));   // values >= 0, uint-max valid
    }
}

extern "C" void kernel_launch(void* const* d_in, const int* in_sizes, int n_in,
                              void* d_out, int out_size, void* d_ws, size_t ws_size,
                              hipStream_t stream) {
    const float* x  = (const float*)d_in[0];   // (32, 8, 2048) fp32
    const float* sh = (const float*)d_in[1];   // (8, 512, 64) fp32
    float* out = (float*)d_out;                // (32, 1, 512) fp32

    // workspace: Bp 512KB | invn 2MB | xh0 ~1.06MB | xh1 ~1.06MB
    _Float16* Bp   = (_Float16*)d_ws;
    float*    invn = (float*)((char*)d_ws + (512 << 10));
    _Float16* xh0  = (_Float16*)((char*)d_ws + (512 << 10) + (2 << 20));
    _Float16* xh1  = xh0 + (size_t)B_ * C_ * XS_;

    prep_k<<<dim3(384), dim3(256), 0, stream>>>(x, sh, Bp, invn, xh0, xh1, out);
    mcs_k<<<dim3(8, 8, B_), dim3(256), 0, stream>>>(xh0, xh1, Bp, invn, out);
}